// Round 8
// baseline (2858.810 us; speedup 1.0000x reference)
//
#include <hip/hip_runtime.h>
#include <hip/hip_bf16.h>
#include <math.h>

// Problem constants
#define Bz 32
#define Nn 128
#define Hh 256
#define Dd 256
#define Ff 512
#define Gg 768
#define NT 512          // 8 waves per block; 256 blocks = 32 batches x 8 col-slices

typedef short v8s __attribute__((ext_vector_type(8)));   // 8 bf16
typedef float f4  __attribute__((ext_vector_type(4)));   // MFMA C/D
#define MFMA(a,b,c) __builtin_amdgcn_mfma_f32_16x16x32_bf16(a,b,c,0,0,0)

// Workspace layout (float elements)
#define WS_H0    0                          // [B][256]
#define WS_GH0   (WS_H0 + Bz*Hh)            // [B][768]
#define WS_ZW1   (WS_GH0 + Bz*Gg)           // [B][512]
#define WS_XH    (WS_ZW1 + Bz*Ff)           // [B][256]   h_prov exchange
#define WS_PSX   (WS_XH + Bz*Hh)            // [B][256]   psum exchange
#define WS_LOGP  (WS_PSX + Bz*Hh)           // [B][8][128] logit partials
#define WS_BAR   (WS_LOGP + Bz*8*Nn)        // [B][32] uint barrier counters
#define WS_XS    (WS_BAR + Bz*32)           // [B][8mt][8ks][128] u64 state exchange
#define WS_WB    (WS_XS + Bz*16384)         // [160][8][64][4] uint B-frag packed weights
#define WS_TOTAL (WS_WB + 160*2048)

// LDS layout (bytes) — total <= 163840
#define SM_SW    0         // [10 lt][8 ks][64 lane] uint4 : 6 Wh-tiles + 4 W1b-tiles (81920)
#define SM_SST   81920     // ushort[8mt][8ks][512] bf16 state mirror (65536)
#define SM_NLDS  147456    // ushort[8mt][512] new-state own-slice staging (8192)
#define SM_PS    155648    // float[256]
#define SM_HPF   156672    // float[256]
#define SM_GX1   157696    // float[96]
#define SM_GX2   158080    // float[96]
#define SM_BASE  158464    // float[64]
#define SM_BXS   158720    // float[96]
#define SM_BHS   159104    // float[96]
#define SM_GH0S  159488    // float[96]
#define SM_ZB1S  159872    // float[64]
#define SM_H0S   160128    // float[32]
#define SM_PSN   160256    // float[32]
#define SM_LOGI  160384    // float[128]
#define SM_ROWT  160896    // float[128]
#define SM_AMASK 161408    // uint[128][4]
#define SM_ANCW  163456    // uint[4]
#define SMEM_SZ  163488

__device__ __forceinline__ unsigned short f2bf(float x) {
  unsigned u = __float_as_uint(x);
  u = u + 0x7fffu + ((u >> 16) & 1u);   // RNE
  return (unsigned short)(u >> 16);
}
__device__ __forceinline__ unsigned pack2(float e, float o) {
  return (unsigned)f2bf(e) | ((unsigned)f2bf(o) << 16);
}
__device__ __forceinline__ unsigned pkbf(float x, float y) {
  __hip_bfloat162 h = __float22bfloat162_rn(make_float2(x, y));
  union { __hip_bfloat162 h; unsigned u; } c; c.h = h; return c.u;
}
__device__ __forceinline__ float bf2f(unsigned short s) {
  return __uint_as_float(((unsigned)s) << 16);
}
__device__ __forceinline__ float sigm(float x) { return 1.0f / (1.0f + __expf(-x)); }
__device__ __forceinline__ float tanh_fast(float x) { return 2.0f / (1.0f + __expf(-2.0f*x)) - 1.0f; }
__device__ __forceinline__ v8s u4v(uint4 q) { union { uint4 q; v8s v; } c; c.q = q; return c.v; }

// Relaxed AGENT atomics (coherent point, no L2 writeback/invalidate)
__device__ __forceinline__ void ast32(unsigned* p, unsigned v) {
  __hip_atomic_store(p, v, __ATOMIC_RELAXED, __HIP_MEMORY_SCOPE_AGENT);
}
__device__ __forceinline__ unsigned ald32(const unsigned* p) {
  return __hip_atomic_load(p, __ATOMIC_RELAXED, __HIP_MEMORY_SCOPE_AGENT);
}
__device__ __forceinline__ void ast64(unsigned long long* p, unsigned long long v) {
  __hip_atomic_store(p, v, __ATOMIC_RELAXED, __HIP_MEMORY_SCOPE_AGENT);
}
__device__ __forceinline__ unsigned long long ald64(const unsigned long long* p) {
  return __hip_atomic_load(p, __ATOMIC_RELAXED, __HIP_MEMORY_SCOPE_AGENT);
}

// split barrier: signal early, wait late (overlap compute with barrier latency)
__device__ __forceinline__ void bsig(unsigned* cnt)
{
  __builtin_amdgcn_s_waitcnt(0x0F70);   // vmcnt(0): this thread's stores done
  __syncthreads();
  if (threadIdx.x == 0)
    __hip_atomic_fetch_add(cnt, 1u, __ATOMIC_RELAXED, __HIP_MEMORY_SCOPE_AGENT);
}
__device__ __forceinline__ void bwait(unsigned* cnt, unsigned& seq)
{
  seq += 8;
  if (threadIdx.x == 0) {
    while (__hip_atomic_load(cnt, __ATOMIC_RELAXED, __HIP_MEMORY_SCOPE_AGENT) < seq)
      __builtin_amdgcn_s_sleep(2);
  }
  __syncthreads();
}

// ---------- prep 1: output L, zero barriers, pack weights ----------
__global__ void __launch_bounds__(256) prep_init(
    const int* __restrict__ tg, const float* __restrict__ Wx,
    const float* __restrict__ Wh, const float* __restrict__ W1,
    float* __restrict__ ws, float* __restrict__ out)
{
  const int stride = gridDim.x * blockDim.x;
  const int t0 = blockIdx.x * blockDim.x + threadIdx.x;

  for (int i = t0; i < Bz*Nn*Nn; i += stride) {         // L = tril(targets, -1)
    int col = i & (Nn-1), row = (i >> 7) & (Nn-1);
    out[i] = (col < row) ? (float)tg[i] : 0.0f;
  }
  for (int i = t0; i < Bz; i += stride) out[Bz*Nn*Nn + i] = 0.0f;

  unsigned* BARu = (unsigned*)(ws + WS_BAR);
  for (int i = t0; i < Bz*32; i += stride) BARu[i] = 0u;

  // B-frag packing: uint (lane l, word jw) = bf16pair W[k][n],W[k+1][n];
  // k = ks*32 + (l>>4)*8 + 2*jw ; n = tile_local*16 + (l&15)
  // regions: [0,48) Wh | [48,80) W1b | [80,128) Wx | [128,160) W1a
  unsigned* Wb = (unsigned*)(ws + WS_WB);
  for (int i = t0; i < 160*2048; i += stride) {
    int jw = i & 3, l = (i >> 2) & 63, ks = (i >> 8) & 7, nt = i >> 11;
    int k = ks*32 + (l >> 4)*8 + 2*jw;
    int n16 = l & 15;
    float lo, hi;
    if (nt < 48)       { int c = nt*16 + n16;        lo = Wh[k*Gg + c];      hi = Wh[(k+1)*Gg + c]; }
    else if (nt < 80)  { int f = (nt-48)*16 + n16;   lo = W1[(Hh+k)*Ff + f]; hi = W1[(Hh+k+1)*Ff + f]; }
    else if (nt < 128) { int c = (nt-80)*16 + n16;   lo = Wx[k*Gg + c];      hi = Wx[(k+1)*Gg + c]; }
    else               { int f = (nt-128)*16 + n16;  lo = W1[k*Ff + f];      hi = W1[(k+1)*Ff + f]; }
    Wb[i] = pack2(lo, hi);
  }
}

// ---------- prep 2: per-batch h0, gh0 = h0@Wh+bh, zW1 = z@W1c ----------
__global__ void __launch_bounds__(256) prep_batch(
    const float* __restrict__ z, const float* __restrict__ Wi,
    const float* __restrict__ bi, const float* __restrict__ Wh,
    const float* __restrict__ bh, const float* __restrict__ W1,
    float* __restrict__ ws)
{
  const int b = blockIdx.x, tid = threadIdx.x;
  __shared__ float zs[Dd], h0s[Hh];
  zs[tid] = z[b*Dd + tid];
  __syncthreads();
  float acc = bi[tid];
  for (int d = 0; d < Dd; ++d) acc = fmaf(zs[d], Wi[d*Hh + tid], acc);
  const float h0 = tanhf(acc);
  h0s[tid] = h0;
  ws[WS_H0 + b*Hh + tid] = h0;
  __syncthreads();
  for (int g = tid; g < Gg; g += 256) {
    float a = bh[g];
    for (int h = 0; h < Hh; ++h) a = fmaf(h0s[h], Wh[h*Gg + g], a);
    ws[WS_GH0 + b*Gg + g] = a;
  }
  for (int f = tid; f < Ff; f += 256) {
    float a = 0.0f;
    for (int d = 0; d < Dd; ++d) a = fmaf(zs[d], W1[(2*Hh + d)*Ff + f], a);
    ws[WS_ZW1 + b*Ff + f] = a;
  }
}

// M=1-replicated A-fragments from one fp32 LDS vector
__device__ __forceinline__ void build_mv(const float* __restrict__ vec, int quad, v8s* av)
{
  #pragma unroll
  for (int ks = 0; ks < 8; ++ks) {
    const float4 a = *(const float4*)(vec + ks*32 + quad*8);
    const float4 c = *(const float4*)(vec + ks*32 + quad*8 + 4);
    union { unsigned u[4]; v8s v; } cv;
    cv.u[0] = pkbf(a.x, a.y); cv.u[1] = pkbf(a.z, a.w);
    cv.u[2] = pkbf(c.x, c.y); cv.u[3] = pkbf(c.z, c.w);
    av[ks] = cv.v;
  }
}
__device__ __forceinline__ void build_mv2(const float* __restrict__ va,
                                          const float* __restrict__ vb, int quad, v8s* av)
{
  #pragma unroll
  for (int ks = 0; ks < 8; ++ks) {
    const float4 a = *(const float4*)(va + ks*32 + quad*8);
    const float4 b = *(const float4*)(vb + ks*32 + quad*8);
    const float4 c = *(const float4*)(va + ks*32 + quad*8 + 4);
    const float4 d = *(const float4*)(vb + ks*32 + quad*8 + 4);
    union { unsigned u[4]; v8s v; } cv;
    cv.u[0] = pkbf(a.x+b.x, a.y+b.y); cv.u[1] = pkbf(a.z+b.z, a.w+b.w);
    cv.u[2] = pkbf(c.x+d.x, c.y+d.y); cv.u[3] = pkbf(c.z+d.z, c.w+d.w);
    av[ks] = cv.v;
  }
}

// GRU pair GEMM: tiles mt0/mt1 share one B-stream (6 chains each)
__device__ __forceinline__ void gemm_gru_pair(
    const unsigned short* SST, const uint4* SW4, int lane,
    int mt0, bool do0, int mt1, bool do1, f4* acc)
{
  v8s a0[8], a1[8];
  if (do0) {
    #pragma unroll
    for (int ks = 0; ks < 8; ++ks) a0[ks] = *(const v8s*)(SST + (mt0*8 + ks)*512 + lane*8);
  }
  if (do1) {
    #pragma unroll
    for (int ks = 0; ks < 8; ++ks) a1[ks] = *(const v8s*)(SST + (mt1*8 + ks)*512 + lane*8);
  }
  #pragma unroll
  for (int ks = 0; ks < 8; ++ks) {
    const v8s b0 = u4v(SW4[(0*8 + ks)*64 + lane]);
    const v8s b1 = u4v(SW4[(1*8 + ks)*64 + lane]);
    const v8s b2 = u4v(SW4[(2*8 + ks)*64 + lane]);
    const v8s b3 = u4v(SW4[(3*8 + ks)*64 + lane]);
    const v8s b4 = u4v(SW4[(4*8 + ks)*64 + lane]);
    const v8s b5 = u4v(SW4[(5*8 + ks)*64 + lane]);
    if (do0) {
      acc[0] = MFMA(a0[ks], b0, acc[0]); acc[1] = MFMA(a0[ks], b1, acc[1]);
      acc[2] = MFMA(a0[ks], b2, acc[2]); acc[3] = MFMA(a0[ks], b3, acc[3]);
      acc[4] = MFMA(a0[ks], b4, acc[4]); acc[5] = MFMA(a0[ks], b5, acc[5]);
    }
    if (do1) {
      acc[6] = MFMA(a1[ks], b0, acc[6]); acc[7]  = MFMA(a1[ks], b1, acc[7]);
      acc[8] = MFMA(a1[ks], b2, acc[8]); acc[9]  = MFMA(a1[ks], b3, acc[9]);
      acc[10]= MFMA(a1[ks], b4, acc[10]); acc[11]= MFMA(a1[ks], b5, acc[11]);
    }
  }
}

// ---------- main: 256 blocks (batch b = blk%32, slice r = blk/32) ----------
__global__ void __launch_bounds__(NT, 2) decoder_main(
    const int* __restrict__ tg,
    const float* __restrict__ bx, const float* __restrict__ bh,
    const float* __restrict__ b1, const float* __restrict__ W2,
    const float* __restrict__ b2,
    float* __restrict__ ws, float* __restrict__ out)
{
  const int blk = blockIdx.x;
  const int b = blk & 31, r = blk >> 5;
  const int tid = threadIdx.x;
  const int lane = tid & 63, wv = tid >> 6;
  const int c16 = lane & 15, quad = lane >> 4;

  extern __shared__ char smem[];
  uint4* SW4 = (uint4*)(smem + SM_SW);
  unsigned short* SST = (unsigned short*)(smem + SM_SST);
  unsigned long long* SST64 = (unsigned long long*)(smem + SM_SST);
  unsigned short* NLDS = (unsigned short*)(smem + SM_NLDS);
  unsigned* NLDSu = (unsigned*)(smem + SM_NLDS);
  unsigned long long* NLDS64 = (unsigned long long*)(smem + SM_NLDS);
  float* PS   = (float*)(smem + SM_PS);
  float* HPF  = (float*)(smem + SM_HPF);
  float* GX1  = (float*)(smem + SM_GX1);
  float* GX2  = (float*)(smem + SM_GX2);
  float* BASE = (float*)(smem + SM_BASE);
  float* BXS  = (float*)(smem + SM_BXS);
  float* BHS  = (float*)(smem + SM_BHS);
  float* GH0S = (float*)(smem + SM_GH0S);
  float* ZB1S = (float*)(smem + SM_ZB1S);
  float* H0S  = (float*)(smem + SM_H0S);
  float* PSN  = (float*)(smem + SM_PSN);
  float* LOGI = (float*)(smem + SM_LOGI);
  float* ROWT = (float*)(smem + SM_ROWT);
  unsigned* AMASK = (unsigned*)(smem + SM_AMASK);
  unsigned* ANCW = (unsigned*)(smem + SM_ANCW);

  const float* __restrict__ h0g  = ws + WS_H0  + b*Hh;
  const float* __restrict__ gh0g = ws + WS_GH0 + b*Gg;
  const float* __restrict__ zW1g = ws + WS_ZW1 + b*Ff;
  unsigned* XHg  = (unsigned*)(ws + WS_XH) + b*Hh;
  unsigned long long* XH64 = (unsigned long long*)((unsigned*)(ws + WS_XH) + b*Hh);
  unsigned long long* PSX64 = (unsigned long long*)((unsigned*)(ws + WS_PSX) + b*Hh);
  unsigned long long* LOGP64 = (unsigned long long*)((unsigned*)(ws + WS_LOGP) + b*8*Nn);
  unsigned* LOGPg = (unsigned*)(ws + WS_LOGP) + b*8*Nn;
  unsigned* bar = (unsigned*)(ws + WS_BAR) + b*32;
  unsigned long long* XS64 = (unsigned long long*)(ws + WS_XS) + b*8192;  // [8mt][8ks][128]
  const uint4* WB4 = (const uint4*)(ws + WS_WB);

  // ---- prologue ----
  for (int i = tid; i < 16384; i += NT) ((unsigned*)SST)[i] = 0u;   // zero mirror
  for (int i = tid; i < 5120; i += NT) {   // weight slices -> LDS (10 tiles)
    const int lt = i >> 9, q = i & 511;
    int gt;
    if (lt < 6) { const int gate = lt >> 1, tt = lt & 1; gt = gate*16 + 2*r + tt; }
    else        { gt = 48 + 4*r + (lt - 6); }
    SW4[lt*512 + q] = WB4[gt*512 + q];
  }
  if (tid < Hh) PS[tid] = h0g[tid];
  if (tid < 32) H0S[tid] = h0g[32*r + tid];
  if (tid < 96) {
    const int g = tid >> 5, hcl = tid & 31;
    const int col = g*256 + 32*r + hcl;
    BXS[tid] = bx[col]; BHS[tid] = bh[col]; GH0S[tid] = gh0g[col];
  }
  if (tid >= 96 && tid < 160) { const int f = 64*r + (tid - 96); ZB1S[tid-96] = zW1g[f] + b1[f]; }
  for (int i = tid; i < Nn*4; i += NT) AMASK[i] = 0u;
  float w2r[4];
  #pragma unroll
  for (int ft = 0; ft < 4; ++ft) w2r[ft] = W2[64*r + ft*16 + c16];
  const float b2v = b2[0];
  unsigned bseq = 0;
  __syncthreads();
  if (tid < Hh) {   // mirror row 0 = h0
    const int c = tid;
    SST[(c>>5)*512 + ((c>>3)&3)*128 + (c&7)] = f2bf(PS[c]);
  }
  __syncthreads();

  for (int t = 1; t < Nn; ++t) {
    const float invt  = 1.0f / (float)t;
    const float invt1 = 1.0f / (float)(t + 1);
    const int Mtot = (t + 16) >> 4;     // GRU rows 0..t
    const int Mlog = (t + 15) >> 4;     // logit rows 0..t-1
    const int mtc = Mtot - 1;           // tile holding row t (deferred for GRU)

    // ---- pre-barrier: phase A matvec (waves 0-5) || aux loads (waves 6-7) ----
    if (wv < 6) {
      v8s av[8]; build_mv(PS, quad, av);
      const int g = wv >> 1, tt = wv & 1;
      const uint4* Bp = WB4 + (80 + g*16 + 2*r + tt)*512 + lane;
      f4 c = {0.0f,0.0f,0.0f,0.0f};
      #pragma unroll
      for (int ks = 0; ks < 8; ++ks) c = MFMA(av[ks], u4v(Bp[ks*64]), c);
      if (quad == 0) GX1[g*32 + tt*16 + c16] = c[0];
    } else {
      const int j = tid - 384;
      ROWT[j] = (j < t) ? (float)tg[b*Nn*Nn + t*Nn + j] : 0.0f;
      LOGI[j] = 0.0f;
      if (j < 32) PSN[j] = 0.0f;
      if (j < 4) ANCW[j] = 0u;
    }
    __syncthreads();

    // h_prov slice -> exchange; ancestor OR (local AMASK, all blocks)
    if (tid < 32) {
      const int hcl = tid;
      const float gxr = GX1[hcl]*invt    + BXS[hcl];
      const float gxu = GX1[32+hcl]*invt + BXS[32+hcl];
      const float gxn = GX1[64+hcl]*invt + BXS[64+hcl];
      const float rv = sigm(gxr + GH0S[hcl]);
      const float uv = sigm(gxu + GH0S[32+hcl]);
      const float nv = tanh_fast(gxn + rv*GH0S[64+hcl]);
      ast32(XHg + 32*r + hcl, __float_as_uint((1.0f-uv)*nv + uv*H0S[hcl]));
    }
    if (tid < Nn && tid < t && ROWT[tid] > 0.5f) {
      atomicOr(&ANCW[0], AMASK[tid*4+0]); atomicOr(&ANCW[1], AMASK[tid*4+1]);
      atomicOr(&ANCW[2], AMASK[tid*4+2]); atomicOr(&ANCW[3], AMASK[tid*4+3]);
    }
    bsig(bar);   // B1 signal (h_prov stores drained)

    // ---- GEMM pass on OLD states, overlapped with B1 latency ----
    f4 acc[12];
    #pragma unroll
    for (int i = 0; i < 12; ++i) acc[i] = (f4){0.0f,0.0f,0.0f,0.0f};
    const bool isGRU = (wv < 4);
    const int mt0 = isGRU ? 2*wv : 2*(wv - 4);
    const int mt1 = mt0 + 1;
    if (isGRU) {
      gemm_gru_pair(SST, SW4, lane, mt0, mt0 < mtc, mt1, mt1 < mtc, acc);
    } else {
      const bool do0 = (mt0 < Mlog), do1 = (mt1 < Mlog);
      v8s a0[8], a1[8];
      if (do0) {
        #pragma unroll
        for (int ks = 0; ks < 8; ++ks) a0[ks] = *(const v8s*)(SST + (mt0*8 + ks)*512 + lane*8);
      }
      if (do1) {
        #pragma unroll
        for (int ks = 0; ks < 8; ++ks) a1[ks] = *(const v8s*)(SST + (mt1*8 + ks)*512 + lane*8);
      }
      #pragma unroll
      for (int ks = 0; ks < 8; ++ks) {
        const v8s c0 = u4v(SW4[(6*8 + ks)*64 + lane]);
        const v8s c1 = u4v(SW4[(7*8 + ks)*64 + lane]);
        const v8s c2 = u4v(SW4[(8*8 + ks)*64 + lane]);
        const v8s c3 = u4v(SW4[(9*8 + ks)*64 + lane]);
        if (do0) {
          acc[0] = MFMA(a0[ks], c0, acc[0]); acc[1] = MFMA(a0[ks], c1, acc[1]);
          acc[2] = MFMA(a0[ks], c2, acc[2]); acc[3] = MFMA(a0[ks], c3, acc[3]);
        }
        if (do1) {
          acc[4] = MFMA(a1[ks], c0, acc[4]); acc[5] = MFMA(a1[ks], c1, acc[5]);
          acc[6] = MFMA(a1[ks], c2, acc[6]); acc[7] = MFMA(a1[ks], c3, acc[7]);
        }
      }
    }
    bwait(bar, bseq);   // B1 wait

    // ---- gather h_prov ----
    if (tid < 128) {
      const unsigned long long v = ald64(XH64 + tid);
      HPF[2*tid]   = __uint_as_float((unsigned)v);
      HPF[2*tid+1] = __uint_as_float((unsigned)(v >> 32));
    }
    __syncthreads();

    // ---- mirror row t (tid<256) || NLDS chunk zero (tid>=256); AMASK row t; matvecs ----
    if (tid < 256) {
      const int c = tid;
      SST[(mtc*8 + (c>>5))*512 + (((c>>3)&3)*16 + (t&15))*8 + (c&7)] = f2bf(HPF[c]);
    } else if (tid < 512) {
      NLDSu[mtc*256 + (tid - 256)] = 0u;
    }
    if (wv < 2) {
      const unsigned long long bal = __ballot(tid < t && ROWT[tid] > 0.5f);
      if (lane == 0) {
        AMASK[t*4 + 2*wv]     = (unsigned)bal         | ANCW[2*wv];
        AMASK[t*4 + 2*wv + 1] = (unsigned)(bal >> 32) | ANCW[2*wv + 1];
      }
    }
    for (int j = wv; j < 10; j += 8) {
      if (j < 6) {
        v8s av[8]; build_mv2(PS, HPF, quad, av);
        const int g = j >> 1, tt = j & 1;
        const uint4* Bp = WB4 + (80 + g*16 + 2*r + tt)*512 + lane;
        f4 c = {0.0f,0.0f,0.0f,0.0f};
        #pragma unroll
        for (int ks = 0; ks < 8; ++ks) c = MFMA(av[ks], u4v(Bp[ks*64]), c);
        if (quad == 0) GX2[g*32 + tt*16 + c16] = c[0]*invt1 + BXS[g*32 + tt*16 + c16];
      } else {
        v8s av[8]; build_mv(HPF, quad, av);
        const int ft = j - 6;
        const uint4* Bp = WB4 + (128 + 4*r + ft)*512 + lane;
        f4 c = {0.0f,0.0f,0.0f,0.0f};
        #pragma unroll
        for (int ks = 0; ks < 8; ++ks) c = MFMA(av[ks], u4v(Bp[ks*64]), c);
        if (quad == 0) BASE[ft*16 + c16] = c[0] + ZB1S[ft*16 + c16];
      }
    }
    __syncthreads();   // row-t, NLDS zero, GX2/BASE ready

    // ---- deferred GRU GEMM for tile mtc (row t now in mirror) ----
    if (isGRU && wv == (mtc >> 1)) {
      gemm_gru_pair(SST, SW4, lane, mt0, mtc == mt0, mt1, mtc == mt1, acc);
    }

    // ---- epilogues ----
    if (isGRU) {
      #pragma unroll
      for (int s = 0; s < 2; ++s) {
        const int mt = s ? mt1 : mt0;
        if (mt < Mtot) {
          const f4* ac = acc + 6*s;
          #pragma unroll
          for (int ct = 0; ct < 2; ++ct) {
            const int hcl = ct*16 + c16;
            const f4 cr = ac[0 + ct], cu = ac[2 + ct], cn = ac[4 + ct];
            const float gxr = GX2[hcl], gxu = GX2[32+hcl], gxn = GX2[64+hcl];
            const float bhr = BHS[hcl], bhu = BHS[32+hcl], bhn = BHS[64+hcl];
            float colsum = 0.0f;
            #pragma unroll
            for (int rg = 0; rg < 4; ++rg) {
              const int row = mt*16 + quad*4 + rg;
              if (row <= t) {
                const int spi = ((hcl>>3)*16 + quad*4 + rg)*8 + (hcl & 7);
                const float old = bf2f(SST[(mt*8 + r)*512 + spi]);
                const float rv = sigm(gxr + cr[rg] + bhr);
                const float uv = sigm(gxu + cu[rg] + bhu);
                const float nv = tanh_fast(gxn + rv*(cn[rg] + bhn));
                const float ns = (1.0f-uv)*nv + uv*old;
                NLDS[mt*512 + spi] = f2bf(ns);
                colsum += ns;
              }
            }
            colsum += __shfl_down(colsum, 16);
            colsum += __shfl_down(colsum, 32);
            if (lane < 16) atomicAdd(&PSN[ct*16 + lane], colsum);
          }
        }
      }
    } else {
      #pragma unroll
      for (int s = 0; s < 2; ++s) {
        const int mt = s ? mt1 : mt0;
        if (mt < Mlog) {
          const f4* ac = acc + 4*s;
          #pragma unroll
          for (int rg = 0; rg < 4; ++rg) {
            float v = fmaxf(ac[0][rg] + BASE[c16],    0.0f)*w2r[0]
                    + fmaxf(ac[1][rg] + BASE[16+c16], 0.0f)*w2r[1]
                    + fmaxf(ac[2][rg] + BASE[32+c16], 0.0f)*w2r[2]
                    + fmaxf(ac[3][rg] + BASE[48+c16], 0.0f)*w2r[3];
            v += __shfl_xor(v, 1); v += __shfl_xor(v, 2);
            v += __shfl_xor(v, 4); v += __shfl_xor(v, 8);
            const int row = mt*16 + quad*4 + rg;
            if (c16 == 0 && row < t) atomicAdd(&LOGI[row], v);
          }
        }
      }
    }
    __syncthreads();   // NLDS/PSN/LOGI complete

    // ---- copy-out via relaxed L3 atomics ----
    for (int i = tid; i < Mtot*128; i += NT) {
      const int mt = i >> 7, q = i & 127;
      const unsigned long long v = NLDS64[i];
      ast64(XS64 + (mt*8 + r)*128 + q, v);
      SST64[(mt*8 + r)*128 + q] = v;            // own chunk updated locally
    }
    if (tid < 64) ast64(LOGP64 + r*64 + tid, ((const unsigned long long*)LOGI)[tid]);
    else if (tid < 80) ast64(PSX64 + r*16 + (tid - 64), ((const unsigned long long*)PSN)[tid - 64]);
    bsig(bar);          // B2 signal
    bwait(bar, bseq);   // B2 wait

    // ---- refresh mirror + psum; duty block (t&7) computes ll ----
    for (int i = tid; i < Mtot*1024; i += NT) {
      const int ks = (i >> 7) & 7;
      if (ks != r) SST64[i] = ald64(XS64 + i);
    }
    if (tid < 128) {
      const unsigned long long v = ald64(PSX64 + tid);
      PS[2*tid]   = __uint_as_float((unsigned)v);
      PS[2*tid+1] = __uint_as_float((unsigned)(v >> 32));
    }
    if (r == (t & 7)) {
      float term = 0.0f;
      if (tid < t) {
        float lsum = b2v;
        #pragma unroll
        for (int rr = 0; rr < 8; ++rr)
          lsum += __uint_as_float(ald32(LOGPg + rr*Nn + tid));
        const float anc = (float)((ANCW[tid >> 5] >> (tid & 31)) & 1u);
        float q = sigm(lsum) * (1.0f - 0.5f*anc);
        q = fminf(fmaxf(q, 1e-6f), 1.0f - 1e-6f);
        term = ROWT[tid]*logf(q) + (1.0f - ROWT[tid])*log1pf(-q);
      }
      if (wv < 2) {
        #pragma unroll
        for (int off = 32; off; off >>= 1) term += __shfl_down(term, off);
        if (lane == 0) atomicAdd(&out[Bz*Nn*Nn + b], term);
      }
    }
    __syncthreads();
  }
}

extern "C" void kernel_launch(void* const* d_in, const int* in_sizes, int n_in,
                              void* d_out, int out_size, void* d_ws, size_t ws_size,
                              hipStream_t stream)
{
  const float* z  = (const float*)d_in[0];
  const int*   tg = (const int*)  d_in[1];
  const float* Wi = (const float*)d_in[2];
  const float* bi = (const float*)d_in[3];
  const float* Wx = (const float*)d_in[4];
  const float* Wh = (const float*)d_in[5];
  const float* bx = (const float*)d_in[6];
  const float* bh = (const float*)d_in[7];
  const float* W1 = (const float*)d_in[8];
  const float* b1 = (const float*)d_in[9];
  const float* W2 = (const float*)d_in[10];
  const float* b2 = (const float*)d_in[11];
  float* out = (float*)d_out;
  float* ws  = (float*)d_ws;

  hipFuncSetAttribute((const void*)decoder_main,
                      hipFuncAttributeMaxDynamicSharedMemorySize, SMEM_SZ);

  hipLaunchKernelGGL(prep_init, dim3(512), dim3(256), 0, stream, tg, Wx, Wh, W1, ws, out);
  hipLaunchKernelGGL(prep_batch, dim3(Bz), dim3(256), 0, stream, z, Wi, bi, Wh, bh, W1, ws);

  void* args[] = { (void*)&tg, (void*)&bx, (void*)&bh, (void*)&b1,
                   (void*)&W2, (void*)&b2, (void*)&ws, (void*)&out };
  hipLaunchCooperativeKernel((void*)decoder_main, dim3(256), dim3(NT),
                             args, SMEM_SZ, stream);
}

// Round 9
// 1982.733 us; speedup vs baseline: 1.4419x; 1.4419x over previous
//
#include <hip/hip_runtime.h>
#include <hip/hip_bf16.h>
#include <math.h>

// Problem constants
#define Bz 32
#define Nn 128
#define Hh 256
#define Dd 256
#define Ff 512
#define Gg 768
#define NT 512          // 8 waves per block; 256 blocks = 32 batches x 8 col-slices

typedef short v8s __attribute__((ext_vector_type(8)));   // 8 bf16
typedef float f4  __attribute__((ext_vector_type(4)));   // MFMA C/D
#define MFMA(a,b,c) __builtin_amdgcn_mfma_f32_16x16x32_bf16(a,b,c,0,0,0)

// Workspace layout (float elements)
#define WS_H0    0                          // [B][256]
#define WS_GH0   (WS_H0 + Bz*Hh)            // [B][768]
#define WS_ZW1   (WS_GH0 + Bz*Gg)           // [B][512]
#define WS_XH    (WS_ZW1 + Bz*Ff)           // [B][256]   h_prov exchange
#define WS_PSX   (WS_XH + Bz*Hh)            // [B][256]   psum exchange
#define WS_LOGP  (WS_PSX + Bz*Hh)           // [B][8][128] logit partials
#define WS_BAR   (WS_LOGP + Bz*8*Nn)        // [B][32] uint barrier counters
#define WS_XS    (WS_BAR + Bz*32)           // [B][8mt][8ks][128] u64 state exchange
#define WS_WB    (WS_XS + Bz*16384)         // [160][8][64][4] uint B-frag packed weights
#define WS_TOTAL (WS_WB + 160*2048)

// LDS layout (bytes) — total <= 163840
#define SM_SW    0         // [10 lt][8 ks][64 lane] uint4 : 6 Wh-tiles + 4 W1b-tiles (81920)
#define SM_SST   81920     // ushort[8mt][8ks][512] bf16 state mirror (65536)
#define SM_NLDS  147456    // ushort[8mt][512] new-state own-slice staging (8192)
#define SM_PS    155648    // float[256]
#define SM_HPF   156672    // float[256]
#define SM_GX1   157696    // float[96]
#define SM_GX2   158080    // float[96]
#define SM_BASE  158464    // float[64]
#define SM_BXS   158720    // float[96]
#define SM_BHS   159104    // float[96]
#define SM_GH0S  159488    // float[96]
#define SM_ZB1S  159872    // float[64]
#define SM_H0S   160128    // float[32]
#define SM_PSN   160256    // float[32]
#define SM_LOGI  160384    // float[128]
#define SM_ROWT  160896    // float[128]
#define SM_AMASK 161408    // uint[128][4]
#define SM_ANCW  163456    // uint[4]
#define SMEM_SZ  163488

__device__ __forceinline__ unsigned short f2bf(float x) {
  unsigned u = __float_as_uint(x);
  u = u + 0x7fffu + ((u >> 16) & 1u);   // RNE
  return (unsigned short)(u >> 16);
}
__device__ __forceinline__ unsigned pack2(float e, float o) {
  return (unsigned)f2bf(e) | ((unsigned)f2bf(o) << 16);
}
__device__ __forceinline__ unsigned pkbf(float x, float y) {
  __hip_bfloat162 h = __float22bfloat162_rn(make_float2(x, y));
  union { __hip_bfloat162 h; unsigned u; } c; c.h = h; return c.u;
}
__device__ __forceinline__ float bf2f(unsigned short s) {
  return __uint_as_float(((unsigned)s) << 16);
}
__device__ __forceinline__ float sigm(float x) { return 1.0f / (1.0f + __expf(-x)); }
__device__ __forceinline__ float tanh_fast(float x) { return 2.0f / (1.0f + __expf(-2.0f*x)) - 1.0f; }
__device__ __forceinline__ v8s u4v(uint4 q) { union { uint4 q; v8s v; } c; c.q = q; return c.v; }

// Relaxed AGENT atomics (coherent point, no L2 writeback/invalidate)
__device__ __forceinline__ void ast32(unsigned* p, unsigned v) {
  __hip_atomic_store(p, v, __ATOMIC_RELAXED, __HIP_MEMORY_SCOPE_AGENT);
}
__device__ __forceinline__ unsigned ald32(const unsigned* p) {
  return __hip_atomic_load(p, __ATOMIC_RELAXED, __HIP_MEMORY_SCOPE_AGENT);
}
__device__ __forceinline__ void ast64(unsigned long long* p, unsigned long long v) {
  __hip_atomic_store(p, v, __ATOMIC_RELAXED, __HIP_MEMORY_SCOPE_AGENT);
}
__device__ __forceinline__ unsigned long long ald64(const unsigned long long* p) {
  return __hip_atomic_load(p, __ATOMIC_RELAXED, __HIP_MEMORY_SCOPE_AGENT);
}

// per-batch barrier among 8 blocks: no fences; per-thread vm drain + one relaxed L3 atomic
__device__ __forceinline__ void bbar(unsigned* cnt, unsigned& seq)
{
  __builtin_amdgcn_s_waitcnt(0x0F70);   // vmcnt(0): this thread's stores complete
  __syncthreads();
  seq += 8;
  if (threadIdx.x == 0) {
    __hip_atomic_fetch_add(cnt, 1u, __ATOMIC_RELAXED, __HIP_MEMORY_SCOPE_AGENT);
    while (__hip_atomic_load(cnt, __ATOMIC_RELAXED, __HIP_MEMORY_SCOPE_AGENT) < seq)
      __builtin_amdgcn_s_sleep(1);
  }
  __syncthreads();
}

// ---------- prep 1: output L, zero barriers, pack weights ----------
__global__ void __launch_bounds__(256) prep_init(
    const int* __restrict__ tg, const float* __restrict__ Wx,
    const float* __restrict__ Wh, const float* __restrict__ W1,
    float* __restrict__ ws, float* __restrict__ out)
{
  const int stride = gridDim.x * blockDim.x;
  const int t0 = blockIdx.x * blockDim.x + threadIdx.x;

  for (int i = t0; i < Bz*Nn*Nn; i += stride) {         // L = tril(targets, -1)
    int col = i & (Nn-1), row = (i >> 7) & (Nn-1);
    out[i] = (col < row) ? (float)tg[i] : 0.0f;
  }
  for (int i = t0; i < Bz; i += stride) out[Bz*Nn*Nn + i] = 0.0f;

  unsigned* BARu = (unsigned*)(ws + WS_BAR);
  for (int i = t0; i < Bz*32; i += stride) BARu[i] = 0u;

  // B-frag packing: uint (lane l, word jw) = bf16pair W[k][n],W[k+1][n];
  // k = ks*32 + (l>>4)*8 + 2*jw ; n = tile_local*16 + (l&15)
  // regions: [0,48) Wh | [48,80) W1b | [80,128) Wx | [128,160) W1a
  unsigned* Wb = (unsigned*)(ws + WS_WB);
  for (int i = t0; i < 160*2048; i += stride) {
    int jw = i & 3, l = (i >> 2) & 63, ks = (i >> 8) & 7, nt = i >> 11;
    int k = ks*32 + (l >> 4)*8 + 2*jw;
    int n16 = l & 15;
    float lo, hi;
    if (nt < 48)       { int c = nt*16 + n16;        lo = Wh[k*Gg + c];      hi = Wh[(k+1)*Gg + c]; }
    else if (nt < 80)  { int f = (nt-48)*16 + n16;   lo = W1[(Hh+k)*Ff + f]; hi = W1[(Hh+k+1)*Ff + f]; }
    else if (nt < 128) { int c = (nt-80)*16 + n16;   lo = Wx[k*Gg + c];      hi = Wx[(k+1)*Gg + c]; }
    else               { int f = (nt-128)*16 + n16;  lo = W1[k*Ff + f];      hi = W1[(k+1)*Ff + f]; }
    Wb[i] = pack2(lo, hi);
  }
}

// ---------- prep 2: per-batch h0, gh0 = h0@Wh+bh, zW1 = z@W1c ----------
__global__ void __launch_bounds__(256) prep_batch(
    const float* __restrict__ z, const float* __restrict__ Wi,
    const float* __restrict__ bi, const float* __restrict__ Wh,
    const float* __restrict__ bh, const float* __restrict__ W1,
    float* __restrict__ ws)
{
  const int b = blockIdx.x, tid = threadIdx.x;
  __shared__ float zs[Dd], h0s[Hh];
  zs[tid] = z[b*Dd + tid];
  __syncthreads();
  float acc = bi[tid];
  for (int d = 0; d < Dd; ++d) acc = fmaf(zs[d], Wi[d*Hh + tid], acc);
  const float h0 = tanhf(acc);
  h0s[tid] = h0;
  ws[WS_H0 + b*Hh + tid] = h0;
  __syncthreads();
  for (int g = tid; g < Gg; g += 256) {
    float a = bh[g];
    for (int h = 0; h < Hh; ++h) a = fmaf(h0s[h], Wh[h*Gg + g], a);
    ws[WS_GH0 + b*Gg + g] = a;
  }
  for (int f = tid; f < Ff; f += 256) {
    float a = 0.0f;
    for (int d = 0; d < Dd; ++d) a = fmaf(zs[d], W1[(2*Hh + d)*Ff + f], a);
    ws[WS_ZW1 + b*Ff + f] = a;
  }
}

// M=1-replicated A-fragments from one fp32 LDS vector
__device__ __forceinline__ void build_mv(const float* __restrict__ vec, int quad, v8s* av)
{
  #pragma unroll
  for (int ks = 0; ks < 8; ++ks) {
    const float4 a = *(const float4*)(vec + ks*32 + quad*8);
    const float4 c = *(const float4*)(vec + ks*32 + quad*8 + 4);
    union { unsigned u[4]; v8s v; } cv;
    cv.u[0] = pkbf(a.x, a.y); cv.u[1] = pkbf(a.z, a.w);
    cv.u[2] = pkbf(c.x, c.y); cv.u[3] = pkbf(c.z, c.w);
    av[ks] = cv.v;
  }
}
__device__ __forceinline__ void build_mv2(const float* __restrict__ va,
                                          const float* __restrict__ vb, int quad, v8s* av)
{
  #pragma unroll
  for (int ks = 0; ks < 8; ++ks) {
    const float4 a = *(const float4*)(va + ks*32 + quad*8);
    const float4 b = *(const float4*)(vb + ks*32 + quad*8);
    const float4 c = *(const float4*)(va + ks*32 + quad*8 + 4);
    const float4 d = *(const float4*)(vb + ks*32 + quad*8 + 4);
    union { unsigned u[4]; v8s v; } cv;
    cv.u[0] = pkbf(a.x+b.x, a.y+b.y); cv.u[1] = pkbf(a.z+b.z, a.w+b.w);
    cv.u[2] = pkbf(c.x+d.x, c.y+d.y); cv.u[3] = pkbf(c.z+d.z, c.w+d.w);
    av[ks] = cv.v;
  }
}

// ---------- main: 256 blocks (batch b = blk%32, slice r = blk/32 -> same XCD) ----------
__global__ void __launch_bounds__(NT) decoder_main(
    const int* __restrict__ tg,
    const float* __restrict__ bx, const float* __restrict__ bh,
    const float* __restrict__ b1, const float* __restrict__ W2,
    const float* __restrict__ b2,
    float* __restrict__ ws, float* __restrict__ out)
{
  const int blk = blockIdx.x;
  const int b = blk & 31, r = blk >> 5;
  const int tid = threadIdx.x;
  const int lane = tid & 63, wv = tid >> 6;
  const int c16 = lane & 15, quad = lane >> 4;

  extern __shared__ char smem[];
  uint4* SW4 = (uint4*)(smem + SM_SW);
  unsigned short* SST = (unsigned short*)(smem + SM_SST);
  unsigned long long* SST64 = (unsigned long long*)(smem + SM_SST);
  unsigned short* NLDS = (unsigned short*)(smem + SM_NLDS);
  unsigned* NLDSu = (unsigned*)(smem + SM_NLDS);
  unsigned long long* NLDS64 = (unsigned long long*)(smem + SM_NLDS);
  float* PS   = (float*)(smem + SM_PS);
  float* HPF  = (float*)(smem + SM_HPF);
  float* GX1  = (float*)(smem + SM_GX1);
  float* GX2  = (float*)(smem + SM_GX2);
  float* BASE = (float*)(smem + SM_BASE);
  float* BXS  = (float*)(smem + SM_BXS);
  float* BHS  = (float*)(smem + SM_BHS);
  float* GH0S = (float*)(smem + SM_GH0S);
  float* ZB1S = (float*)(smem + SM_ZB1S);
  float* H0S  = (float*)(smem + SM_H0S);
  float* PSN  = (float*)(smem + SM_PSN);
  float* LOGI = (float*)(smem + SM_LOGI);
  float* ROWT = (float*)(smem + SM_ROWT);
  unsigned* AMASK = (unsigned*)(smem + SM_AMASK);
  unsigned* ANCW = (unsigned*)(smem + SM_ANCW);

  const float* __restrict__ h0g  = ws + WS_H0  + b*Hh;
  const float* __restrict__ gh0g = ws + WS_GH0 + b*Gg;
  const float* __restrict__ zW1g = ws + WS_ZW1 + b*Ff;
  unsigned* XHg  = (unsigned*)(ws + WS_XH) + b*Hh;
  unsigned long long* XH64 = (unsigned long long*)((unsigned*)(ws + WS_XH) + b*Hh);
  unsigned long long* PSX64 = (unsigned long long*)((unsigned*)(ws + WS_PSX) + b*Hh);
  unsigned long long* LOGP64 = (unsigned long long*)((unsigned*)(ws + WS_LOGP) + b*8*Nn);
  unsigned* LOGPg = (unsigned*)(ws + WS_LOGP) + b*8*Nn;
  unsigned* bar = (unsigned*)(ws + WS_BAR) + b*32;
  unsigned long long* XS64 = (unsigned long long*)(ws + WS_XS) + b*8192;  // [8mt][8ks][128]
  const uint4* WB4 = (const uint4*)(ws + WS_WB);

  // ---- prologue ----
  for (int i = tid; i < 16384; i += NT) ((unsigned*)SST)[i] = 0u;   // zero mirror
  for (int i = tid; i < 5120; i += NT) {   // weight slices -> LDS (10 tiles)
    const int lt = i >> 9, q = i & 511;
    int gt;
    if (lt < 6) { const int gate = lt >> 1, tt = lt & 1; gt = gate*16 + 2*r + tt; }
    else        { gt = 48 + 4*r + (lt - 6); }
    SW4[lt*512 + q] = WB4[gt*512 + q];
  }
  if (tid < Hh) PS[tid] = h0g[tid];
  if (tid < 32) H0S[tid] = h0g[32*r + tid];
  if (tid < 96) {
    const int g = tid >> 5, hcl = tid & 31;
    const int col = g*256 + 32*r + hcl;
    BXS[tid] = bx[col]; BHS[tid] = bh[col]; GH0S[tid] = gh0g[col];
  }
  if (tid >= 96 && tid < 160) { const int f = 64*r + (tid - 96); ZB1S[tid-96] = zW1g[f] + b1[f]; }
  for (int i = tid; i < Nn*4; i += NT) AMASK[i] = 0u;
  float w2r[4];
  #pragma unroll
  for (int ft = 0; ft < 4; ++ft) w2r[ft] = W2[64*r + ft*16 + c16];
  const float b2v = b2[0];
  unsigned bseq = 0;
  __syncthreads();
  if (tid < Hh) {   // mirror row 0 = h0
    const int c = tid;
    SST[(c>>5)*512 + ((c>>3)&3)*128 + (c&7)] = f2bf(PS[c]);
  }
  __syncthreads();

  for (int t = 1; t < Nn; ++t) {
    const float invt  = 1.0f / (float)t;
    const float invt1 = 1.0f / (float)(t + 1);
    const int Mtot = (t + 16) >> 4;     // GRU rows 0..t
    const int Mlog = (t + 15) >> 4;     // logit rows 0..t-1
    const int mtc = Mtot - 1;           // tile holding row t

    // ---- phase A: gx1 slice matvec (waves 0-5) || aux init (waves 6-7) ----
    if (wv < 6) {
      v8s av[8]; build_mv(PS, quad, av);
      const int g = wv >> 1, tt = wv & 1;
      const uint4* Bp = WB4 + (80 + g*16 + 2*r + tt)*512 + lane;
      f4 c = {0.0f,0.0f,0.0f,0.0f};
      #pragma unroll
      for (int ks = 0; ks < 8; ++ks) c = MFMA(av[ks], u4v(Bp[ks*64]), c);
      if (quad == 0) GX1[g*32 + tt*16 + c16] = c[0];
    } else {
      const int j = tid - 384;
      ROWT[j] = (j < t) ? (float)tg[b*Nn*Nn + t*Nn + j] : 0.0f;
      LOGI[j] = 0.0f;
      if (j < 32) PSN[j] = 0.0f;
      if (j < 4) ANCW[j] = 0u;
    }
    __syncthreads();

    // h_prov slice -> exchange; ancestor OR (local, all blocks)
    if (tid < 32) {
      const int hcl = tid;
      const float gxr = GX1[hcl]*invt    + BXS[hcl];
      const float gxu = GX1[32+hcl]*invt + BXS[32+hcl];
      const float gxn = GX1[64+hcl]*invt + BXS[64+hcl];
      const float rv = sigm(gxr + GH0S[hcl]);
      const float uv = sigm(gxu + GH0S[32+hcl]);
      const float nv = tanh_fast(gxn + rv*GH0S[64+hcl]);
      ast32(XHg + 32*r + hcl, __float_as_uint((1.0f-uv)*nv + uv*H0S[hcl]));
    }
    if (tid < Nn && tid < t && ROWT[tid] > 0.5f) {
      atomicOr(&ANCW[0], AMASK[tid*4+0]); atomicOr(&ANCW[1], AMASK[tid*4+1]);
      atomicOr(&ANCW[2], AMASK[tid*4+2]); atomicOr(&ANCW[3], AMASK[tid*4+3]);
    }
    bbar(bar, bseq);   // B1: h_prov complete

    // ---- gather h_prov ----
    if (tid < 128) {
      const unsigned long long v = ald64(XH64 + tid);
      HPF[2*tid]   = __uint_as_float((unsigned)v);
      HPF[2*tid+1] = __uint_as_float((unsigned)(v >> 32));
    }
    __syncthreads();

    // ---- mirror row t (tid<256) || NLDS chunk zero (tid>=256); AMASK row t; matvecs ----
    if (tid < 256) {
      const int c = tid;
      SST[(mtc*8 + (c>>5))*512 + (((c>>3)&3)*16 + (t&15))*8 + (c&7)] = f2bf(HPF[c]);
    } else {
      NLDSu[mtc*256 + (tid - 256)] = 0u;
    }
    if (wv < 2) {
      const unsigned long long bal = __ballot(tid < t && ROWT[tid] > 0.5f);
      if (lane == 0) {
        AMASK[t*4 + 2*wv]     = (unsigned)bal         | ANCW[2*wv];
        AMASK[t*4 + 2*wv + 1] = (unsigned)(bal >> 32) | ANCW[2*wv + 1];
      }
    }
    for (int j = wv; j < 10; j += 8) {
      if (j < 6) {
        v8s av[8]; build_mv2(PS, HPF, quad, av);
        const int g = j >> 1, tt = j & 1;
        const uint4* Bp = WB4 + (80 + g*16 + 2*r + tt)*512 + lane;
        f4 c = {0.0f,0.0f,0.0f,0.0f};
        #pragma unroll
        for (int ks = 0; ks < 8; ++ks) c = MFMA(av[ks], u4v(Bp[ks*64]), c);
        if (quad == 0) GX2[g*32 + tt*16 + c16] = c[0]*invt1 + BXS[g*32 + tt*16 + c16];
      } else {
        v8s av[8]; build_mv(HPF, quad, av);
        const int ft = j - 6;
        const uint4* Bp = WB4 + (128 + 4*r + ft)*512 + lane;
        f4 c = {0.0f,0.0f,0.0f,0.0f};
        #pragma unroll
        for (int ks = 0; ks < 8; ++ks) c = MFMA(av[ks], u4v(Bp[ks*64]), c);
        if (quad == 0) BASE[ft*16 + c16] = c[0] + ZB1S[ft*16 + c16];
      }
    }
    __syncthreads();   // row-t, NLDS zero, GX2/BASE ready

    // ---- phase C: paired GEMM jobs (one B-stream per 2 M-tiles; per-ks A loads) ----
    const int nG = (Mtot + 1) >> 1;
    const int nL = (Mlog + 1) >> 1;
    const int njobs = nG + nL;
    for (int j = wv; j < njobs; j += 8) {
      if (j < nG) {
        const int mt0 = 2*j, mt1 = mt0 + 1;
        const bool do1 = (mt1 < Mtot);
        f4 acc[12];
        #pragma unroll
        for (int i = 0; i < 12; ++i) acc[i] = (f4){0.0f,0.0f,0.0f,0.0f};
        #pragma unroll
        for (int ks = 0; ks < 8; ++ks) {
          const v8s a0 = *(const v8s*)(SST + (mt0*8 + ks)*512 + lane*8);
          const v8s b0 = u4v(SW4[(0*8 + ks)*64 + lane]);
          const v8s b1 = u4v(SW4[(1*8 + ks)*64 + lane]);
          const v8s b2 = u4v(SW4[(2*8 + ks)*64 + lane]);
          const v8s b3 = u4v(SW4[(3*8 + ks)*64 + lane]);
          const v8s b4 = u4v(SW4[(4*8 + ks)*64 + lane]);
          const v8s b5 = u4v(SW4[(5*8 + ks)*64 + lane]);
          acc[0] = MFMA(a0, b0, acc[0]); acc[1] = MFMA(a0, b1, acc[1]);
          acc[2] = MFMA(a0, b2, acc[2]); acc[3] = MFMA(a0, b3, acc[3]);
          acc[4] = MFMA(a0, b4, acc[4]); acc[5] = MFMA(a0, b5, acc[5]);
          if (do1) {
            const v8s a1 = *(const v8s*)(SST + (mt1*8 + ks)*512 + lane*8);
            acc[6]  = MFMA(a1, b0, acc[6]);  acc[7]  = MFMA(a1, b1, acc[7]);
            acc[8]  = MFMA(a1, b2, acc[8]);  acc[9]  = MFMA(a1, b3, acc[9]);
            acc[10] = MFMA(a1, b4, acc[10]); acc[11] = MFMA(a1, b5, acc[11]);
          }
        }
        #pragma unroll
        for (int s = 0; s < 2; ++s) {
          if (s == 1 && !do1) break;
          const int mt = s ? mt1 : mt0;
          const f4* ac = acc + 6*s;
          #pragma unroll
          for (int ct = 0; ct < 2; ++ct) {
            const int hcl = ct*16 + c16;
            const f4 cr = ac[0 + ct], cu = ac[2 + ct], cn = ac[4 + ct];
            const float gxr = GX2[hcl], gxu = GX2[32+hcl], gxn = GX2[64+hcl];
            const float bhr = BHS[hcl], bhu = BHS[32+hcl], bhn = BHS[64+hcl];
            float colsum = 0.0f;
            #pragma unroll
            for (int rg = 0; rg < 4; ++rg) {
              const int row = mt*16 + quad*4 + rg;
              if (row <= t) {
                const int spi = ((hcl>>3)*16 + quad*4 + rg)*8 + (hcl & 7);
                const float old = bf2f(SST[(mt*8 + r)*512 + spi]);
                const float rv = sigm(gxr + cr[rg] + bhr);
                const float uv = sigm(gxu + cu[rg] + bhu);
                const float nv = tanh_fast(gxn + rv*(cn[rg] + bhn));
                const float ns = (1.0f-uv)*nv + uv*old;
                NLDS[mt*512 + spi] = f2bf(ns);
                colsum += ns;
              }
            }
            colsum += __shfl_down(colsum, 16);
            colsum += __shfl_down(colsum, 32);
            if (lane < 16) atomicAdd(&PSN[ct*16 + lane], colsum);
          }
        }
      } else {
        const int jj = j - nG;
        const int mt0 = 2*jj, mt1 = mt0 + 1;
        const bool do1 = (mt1 < Mlog);
        f4 acc[8];
        #pragma unroll
        for (int i = 0; i < 8; ++i) acc[i] = (f4){0.0f,0.0f,0.0f,0.0f};
        #pragma unroll
        for (int ks = 0; ks < 8; ++ks) {
          const v8s a0 = *(const v8s*)(SST + (mt0*8 + ks)*512 + lane*8);
          const v8s c0 = u4v(SW4[(6*8 + ks)*64 + lane]);
          const v8s c1 = u4v(SW4[(7*8 + ks)*64 + lane]);
          const v8s c2 = u4v(SW4[(8*8 + ks)*64 + lane]);
          const v8s c3 = u4v(SW4[(9*8 + ks)*64 + lane]);
          acc[0] = MFMA(a0, c0, acc[0]); acc[1] = MFMA(a0, c1, acc[1]);
          acc[2] = MFMA(a0, c2, acc[2]); acc[3] = MFMA(a0, c3, acc[3]);
          if (do1) {
            const v8s a1 = *(const v8s*)(SST + (mt1*8 + ks)*512 + lane*8);
            acc[4] = MFMA(a1, c0, acc[4]); acc[5] = MFMA(a1, c1, acc[5]);
            acc[6] = MFMA(a1, c2, acc[6]); acc[7] = MFMA(a1, c3, acc[7]);
          }
        }
        #pragma unroll
        for (int s = 0; s < 2; ++s) {
          if (s == 1 && !do1) break;
          const int mt = s ? mt1 : mt0;
          const f4* ac = acc + 4*s;
          #pragma unroll
          for (int rg = 0; rg < 4; ++rg) {
            float v = fmaxf(ac[0][rg] + BASE[c16],    0.0f)*w2r[0]
                    + fmaxf(ac[1][rg] + BASE[16+c16], 0.0f)*w2r[1]
                    + fmaxf(ac[2][rg] + BASE[32+c16], 0.0f)*w2r[2]
                    + fmaxf(ac[3][rg] + BASE[48+c16], 0.0f)*w2r[3];
            v += __shfl_xor(v, 1); v += __shfl_xor(v, 2);
            v += __shfl_xor(v, 4); v += __shfl_xor(v, 8);
            const int row = mt*16 + quad*4 + rg;
            if (c16 == 0 && row < t) atomicAdd(&LOGI[row], v);
          }
        }
      }
    }
    __syncthreads();   // NLDS/PSN/LOGI complete

    // ---- copy-out via relaxed L3 atomics ----
    for (int i = tid; i < Mtot*128; i += NT) {
      const int mt = i >> 7, q = i & 127;
      const unsigned long long v = NLDS64[i];
      ast64(XS64 + (mt*8 + r)*128 + q, v);
      SST64[(mt*8 + r)*128 + q] = v;            // own chunk updated locally
    }
    if (tid < 64) ast64(LOGP64 + r*64 + tid, ((const unsigned long long*)LOGI)[tid]);
    else if (tid < 80) ast64(PSX64 + r*16 + (tid - 64), ((const unsigned long long*)PSN)[tid - 64]);
    bbar(bar, bseq);   // B2: states/logits/psum complete

    // ---- refresh mirror + psum; duty block (t&7) computes ll ----
    for (int i = tid; i < Mtot*1024; i += NT) {
      const int ks = (i >> 7) & 7;
      if (ks != r) SST64[i] = ald64(XS64 + i);
    }
    if (tid < 128) {
      const unsigned long long v = ald64(PSX64 + tid);
      PS[2*tid]   = __uint_as_float((unsigned)v);
      PS[2*tid+1] = __uint_as_float((unsigned)(v >> 32));
    }
    if (r == (t & 7)) {
      float term = 0.0f;
      if (tid < t) {
        float lsum = b2v;
        #pragma unroll
        for (int rr = 0; rr < 8; ++rr)
          lsum += __uint_as_float(ald32(LOGPg + rr*Nn + tid));
        const float anc = (float)((ANCW[tid >> 5] >> (tid & 31)) & 1u);
        float q = sigm(lsum) * (1.0f - 0.5f*anc);
        q = fminf(fmaxf(q, 1e-6f), 1.0f - 1e-6f);
        term = ROWT[tid]*logf(q) + (1.0f - ROWT[tid])*log1pf(-q);
      }
      if (wv < 2) {
        #pragma unroll
        for (int off = 32; off; off >>= 1) term += __shfl_down(term, off);
        if (lane == 0) atomicAdd(&out[Bz*Nn*Nn + b], term);
      }
    }
    __syncthreads();
  }
}

extern "C" void kernel_launch(void* const* d_in, const int* in_sizes, int n_in,
                              void* d_out, int out_size, void* d_ws, size_t ws_size,
                              hipStream_t stream)
{
  const float* z  = (const float*)d_in[0];
  const int*   tg = (const int*)  d_in[1];
  const float* Wi = (const float*)d_in[2];
  const float* bi = (const float*)d_in[3];
  const float* Wx = (const float*)d_in[4];
  const float* Wh = (const float*)d_in[5];
  const float* bx = (const float*)d_in[6];
  const float* bh = (const float*)d_in[7];
  const float* W1 = (const float*)d_in[8];
  const float* b1 = (const float*)d_in[9];
  const float* W2 = (const float*)d_in[10];
  const float* b2 = (const float*)d_in[11];
  float* out = (float*)d_out;
  float* ws  = (float*)d_ws;

  hipFuncSetAttribute((const void*)decoder_main,
                      hipFuncAttributeMaxDynamicSharedMemorySize, SMEM_SZ);

  hipLaunchKernelGGL(prep_init, dim3(512), dim3(256), 0, stream, tg, Wx, Wh, W1, ws, out);
  hipLaunchKernelGGL(prep_batch, dim3(Bz), dim3(256), 0, stream, z, Wi, bi, Wh, bh, W1, ws);

  void* args[] = { (void*)&tg, (void*)&bx, (void*)&bh, (void*)&b1,
                   (void*)&W2, (void*)&b2, (void*)&ws, (void*)&out };
  hipLaunchCooperativeKernel((void*)decoder_main, dim3(256), dim3(NT),
                             args, SMEM_SZ, stream);
}